// Round 1
// baseline (152.597 us; speedup 1.0000x reference)
//
#include <hip/hip_runtime.h>
#include <hip/hip_bf16.h>

#define BB 64
#define NN 96
#define FF 16
#define HH 128
#define KK 64
#define LL 3
#define CUTOFF_F 10.0f
#define GAMMA_F 10.0f

// ---------------------------------------------------------------------------
// Kernel 0: W2[l] = Wrbf[l] @ Wpair[l]  ([K,H]@[H,H] -> [K,H])
//           c2[l] = brbf[l] @ Wpair[l] + bpair[l]   ([H])
// One thread per output element; row kk==KK computes the bias row c2.
// ---------------------------------------------------------------------------
__global__ __launch_bounds__(256) void w2_kernel(
    const float* __restrict__ Wrbf, const float* __restrict__ brbf,
    const float* __restrict__ Wpair, const float* __restrict__ bpair,
    float* __restrict__ W2, float* __restrict__ c2)
{
    int idx = blockIdx.x * 256 + threadIdx.x;
    const int total = LL * (KK + 1) * HH;
    if (idx >= total) return;
    int h  = idx % HH;
    int kk = (idx / HH) % (KK + 1);
    int l  = idx / (HH * (KK + 1));
    const float* Wp = Wpair + l * HH * HH;
    if (kk < KK) {
        const float* wr = Wrbf + (l * KK + kk) * HH;
        float acc = 0.f;
        for (int m = 0; m < HH; ++m) acc += wr[m] * Wp[m * HH + h];
        W2[(l * KK + kk) * HH + h] = acc;
    } else {
        const float* br = brbf + l * HH;
        float acc = bpair[l * HH + h];
        for (int m = 0; m < HH; ++m) acc += br[m] * Wp[m * HH + h];
        c2[l * HH + h] = acc;
    }
}

// ---------------------------------------------------------------------------
// Kernel 1: cnt[b] = number of valid atoms in batch b (as float)
// ---------------------------------------------------------------------------
__global__ __launch_bounds__(128) void cnt_kernel(
    const int* __restrict__ batch, float* __restrict__ cnt)
{
    __shared__ float part[2];
    int b = blockIdx.x, t = threadIdx.x;
    float v = (t < NN && batch[b * NN + t] != -1) ? 1.f : 0.f;
    for (int off = 32; off > 0; off >>= 1) v += __shfl_down(v, off);
    if ((t & 63) == 0) part[t >> 6] = v;
    __syncthreads();
    if (t == 0) cnt[b] = part[0] + part[1];
}

// ---------------------------------------------------------------------------
// Kernel 2: S[b,j,k] = sum_{i valid} exp(-gamma*(d(i,j)-c_k)^2)
// One block (1 wave, 64 threads) per (b,j); thread = k.
// ---------------------------------------------------------------------------
__global__ __launch_bounds__(64) void s_kernel(
    const float* __restrict__ R, const int* __restrict__ batch,
    float* __restrict__ S)
{
    int bj = blockIdx.x;
    int b = bj / NN;
    int k = threadIdx.x;
    const float ck = (float)k * (CUTOFF_F / (float)(KK - 1));
    const float xj = R[bj * 3 + 0];
    const float yj = R[bj * 3 + 1];
    const float zj = R[bj * 3 + 2];
    const float* Rb = R + b * NN * 3;
    const int* bt = batch + b * NN;
    float acc = 0.f;
    for (int i = 0; i < NN; ++i) {
        if (bt[i] == -1) continue;
        float dx = Rb[i * 3 + 0] - xj;
        float dy = Rb[i * 3 + 1] - yj;
        float dz = Rb[i * 3 + 2] - zj;
        float d = sqrtf(dx * dx + dy * dy + dz * dz);
        float u = d - ck;
        acc += __expf(-GAMMA_F * u * u);
    }
    S[bj * KK + k] = acc;
}

// ---------------------------------------------------------------------------
// Kernel 3: per-atom MLP chain. 256 threads = 2 atoms in flight x 128 channels;
// GA=8 atoms per block to amortize weight reads (all weights L2-resident).
//   h = X@We + be
//   for l: agg = valid_j * (S@W2[l] + cnt_b*c2[l])
//          h  += silu(agg@Wa1[l]+ba1[l]) @ Wa2[l] + ba2[l]
//   o[b,j] = valid_j * (silu(h@Wo1+bo1) @ Wo2 + bo2)
// ---------------------------------------------------------------------------
#define GA 8
__global__ __launch_bounds__(256) void chain_kernel(
    const float* __restrict__ X, const int* __restrict__ batch,
    const float* __restrict__ We, const float* __restrict__ be,
    const float* __restrict__ Wa1, const float* __restrict__ ba1,
    const float* __restrict__ Wa2, const float* __restrict__ ba2,
    const float* __restrict__ Wo1, const float* __restrict__ bo1,
    const float* __restrict__ Wo2, const float* __restrict__ bo2,
    const float* __restrict__ S, const float* __restrict__ W2,
    const float* __restrict__ c2, const float* __restrict__ cnt,
    float* __restrict__ o_ws)
{
    __shared__ float vbuf[2][HH];
    __shared__ float sS[2][KK];
    __shared__ float part[4];
    const int s  = threadIdx.x >> 7;   // sub-block: which atom in flight
    const int hh = threadIdx.x & 127;  // channel
    const int a0 = blockIdx.x * GA;

    for (int p = 0; p < GA / 2; ++p) {
        const int a = a0 + p * 2 + s;      // flat atom index = b*NN + j
        const int b = a / NN;
        const bool vj = (batch[a] != -1);
        const float cb = cnt[b];

        if (hh < KK) sS[s][hh] = S[a * KK + hh];
        __syncthreads();

        // embedding
        float h = be[hh];
        const float* xr = X + a * FF;
        #pragma unroll
        for (int f = 0; f < FF; ++f) h += xr[f] * We[f * HH + hh];

        for (int l = 0; l < LL; ++l) {
            float agg = 0.f;
            if (vj) {
                agg = cb * c2[l * HH + hh];
                const float* w2 = W2 + l * KK * HH;
                #pragma unroll 8
                for (int k = 0; k < KK; ++k) agg += sS[s][k] * w2[k * HH + hh];
            }
            vbuf[s][hh] = agg;
            __syncthreads();

            float a1 = ba1[l * HH + hh];
            const float* wa1 = Wa1 + l * HH * HH;
            #pragma unroll 8
            for (int m = 0; m < HH; ++m) a1 += vbuf[s][m] * wa1[m * HH + hh];
            float t = a1 / (1.f + __expf(-a1));   // silu
            __syncthreads();
            vbuf[s][hh] = t;
            __syncthreads();

            float h2 = ba2[l * HH + hh];
            const float* wa2 = Wa2 + l * HH * HH;
            #pragma unroll 8
            for (int m = 0; m < HH; ++m) h2 += vbuf[s][m] * wa2[m * HH + hh];
            h += h2;
            __syncthreads();
        }

        vbuf[s][hh] = h;
        __syncthreads();
        float o1 = bo1[hh];
        #pragma unroll 8
        for (int m = 0; m < HH; ++m) o1 += vbuf[s][m] * Wo1[m * HH + hh];
        o1 = o1 / (1.f + __expf(-o1));            // silu
        float contrib = o1 * Wo2[hh];

        // reduce 128 channels (2 waves per sub-block)
        for (int off = 32; off > 0; off >>= 1) contrib += __shfl_down(contrib, off);
        if ((threadIdx.x & 63) == 0) part[threadIdx.x >> 6] = contrib;
        __syncthreads();
        if (hh == 0) {
            float o = part[s * 2] + part[s * 2 + 1] + bo2[0];
            o_ws[a] = vj ? o : 0.f;
        }
        __syncthreads();
    }
}

// ---------------------------------------------------------------------------
// Kernel 4: out[b] = sum_j o[b,j] / cnt[b]
// ---------------------------------------------------------------------------
__global__ __launch_bounds__(128) void reduce_kernel(
    const float* __restrict__ o_ws, const float* __restrict__ cnt,
    float* __restrict__ out)
{
    __shared__ float part[2];
    int b = blockIdx.x, t = threadIdx.x;
    float v = (t < NN) ? o_ws[b * NN + t] : 0.f;
    for (int off = 32; off > 0; off >>= 1) v += __shfl_down(v, off);
    if ((t & 63) == 0) part[t >> 6] = v;
    __syncthreads();
    if (t == 0) out[b] = (part[0] + part[1]) / cnt[b];
}

extern "C" void kernel_launch(void* const* d_in, const int* in_sizes, int n_in,
                              void* d_out, int out_size, void* d_ws, size_t ws_size,
                              hipStream_t stream) {
    const float* X     = (const float*)d_in[0];
    const float* R     = (const float*)d_in[1];
    const int*   batch = (const int*)  d_in[2];
    const float* We    = (const float*)d_in[3];
    const float* be    = (const float*)d_in[4];
    const float* Wrbf  = (const float*)d_in[5];
    const float* brbf  = (const float*)d_in[6];
    const float* Wpair = (const float*)d_in[7];
    const float* bpair = (const float*)d_in[8];
    const float* Wa1   = (const float*)d_in[9];
    const float* ba1   = (const float*)d_in[10];
    const float* Wa2   = (const float*)d_in[11];
    const float* ba2   = (const float*)d_in[12];
    const float* Wo1   = (const float*)d_in[13];
    const float* bo1   = (const float*)d_in[14];
    const float* Wo2   = (const float*)d_in[15];
    const float* bo2   = (const float*)d_in[16];

    float* w   = (float*)d_ws;
    float* S   = w;                        // B*N*K = 393216
    float* W2  = S  + BB * NN * KK;        // L*K*H = 24576
    float* c2  = W2 + LL * KK * HH;        // L*H   = 384
    float* cnt = c2 + LL * HH;             // B     = 64
    float* ow  = cnt + BB;                 // B*N   = 6144
    float* out = (float*)d_out;

    hipLaunchKernelGGL(w2_kernel, dim3((LL * (KK + 1) * HH + 255) / 256), dim3(256),
                       0, stream, Wrbf, brbf, Wpair, bpair, W2, c2);
    hipLaunchKernelGGL(cnt_kernel, dim3(BB), dim3(128), 0, stream, batch, cnt);
    hipLaunchKernelGGL(s_kernel, dim3(BB * NN), dim3(KK), 0, stream, R, batch, S);
    hipLaunchKernelGGL(chain_kernel, dim3(BB * NN / GA), dim3(256), 0, stream,
                       X, batch, We, be, Wa1, ba1, Wa2, ba2, Wo1, bo1, Wo2, bo2,
                       S, W2, c2, cnt, ow);
    hipLaunchKernelGGL(reduce_kernel, dim3(BB), dim3(128), 0, stream, ow, cnt, out);
}

// Round 2
// 74.451 us; speedup vs baseline: 2.0496x; 2.0496x over previous
//
#include <hip/hip_runtime.h>
#include <hip/hip_bf16.h>

#define BB 64
#define NN 96
#define FF 16
#define HH 128
#define KK 64
#define LL 3
#define CUTOFF_F 10.0f
#define GAMMA_F 10.0f

#define W2_BLOCKS 98          // ceil(3*65*128 / 256)
#define CNT_BLOCKS BB
#define S_BLOCKS (BB * NN / 4)

// ---------------------------------------------------------------------------
// pre_kernel (heterogeneous):
//   blocks [0, 98):        W2[l] = Wrbf[l]@Wpair[l], c2[l] = brbf[l]@Wpair[l]+bpair[l]
//   blocks [98, 162):      cnt[b] = #valid atoms
//   blocks [162, 162+1536): S[b,j,k] = sum_{i valid} exp(-g*(d(i,j)-c_k)^2), 4 (b,j) per block
// ---------------------------------------------------------------------------
__global__ __launch_bounds__(256) void pre_kernel(
    const float* __restrict__ Wrbf, const float* __restrict__ brbf,
    const float* __restrict__ Wpair, const float* __restrict__ bpair,
    const int* __restrict__ batch, const float* __restrict__ R,
    float* __restrict__ W2, float* __restrict__ c2,
    float* __restrict__ cnt, float* __restrict__ S)
{
    const int bid = blockIdx.x;
    const int tid = threadIdx.x;
    if (bid < W2_BLOCKS) {
        int idx = bid * 256 + tid;
        const int total = LL * (KK + 1) * HH;
        if (idx >= total) return;
        int h  = idx % HH;
        int kk = (idx / HH) % (KK + 1);
        int l  = idx / (HH * (KK + 1));
        const float* Wp = Wpair + l * HH * HH;
        if (kk < KK) {
            const float* wr = Wrbf + (l * KK + kk) * HH;
            float acc = 0.f;
            #pragma unroll 8
            for (int m = 0; m < HH; ++m) acc += wr[m] * Wp[m * HH + h];
            W2[(l * KK + kk) * HH + h] = acc;
        } else {
            const float* br = brbf + l * HH;
            float acc = bpair[l * HH + h];
            #pragma unroll 8
            for (int m = 0; m < HH; ++m) acc += br[m] * Wp[m * HH + h];
            c2[l * HH + h] = acc;
        }
    } else if (bid < W2_BLOCKS + CNT_BLOCKS) {
        int b = bid - W2_BLOCKS;
        __shared__ int c[4];
        bool v = (tid < NN) && (batch[b * NN + tid] != -1);
        unsigned long long m = __ballot(v);
        if ((tid & 63) == 0) c[tid >> 6] = __popcll(m);
        __syncthreads();
        if (tid == 0) cnt[b] = (float)(c[0] + c[1] + c[2] + c[3]);
    } else {
        int bj = (bid - W2_BLOCKS - CNT_BLOCKS) * 4 + (tid >> 6);
        int b = bj / NN;
        int k = tid & 63;
        const float ck = (float)k * (CUTOFF_F / (float)(KK - 1));
        const float xj = R[bj * 3 + 0];
        const float yj = R[bj * 3 + 1];
        const float zj = R[bj * 3 + 2];
        const float* Rb = R + b * NN * 3;
        const int* bt = batch + b * NN;
        float acc = 0.f;
        for (int i = 0; i < NN; ++i) {
            if (bt[i] == -1) continue;
            float dx = Rb[i * 3 + 0] - xj;
            float dy = Rb[i * 3 + 1] - yj;
            float dz = Rb[i * 3 + 2] - zj;
            float d = sqrtf(dx * dx + dy * dy + dz * dz);
            float u = d - ck;
            acc += __expf(-GAMMA_F * u * u);
        }
        S[bj * KK + k] = acc;
    }
}

// ---------------------------------------------------------------------------
// w3_kernel: W3[l] = W2[l] @ Wa1[l]  ([K,H]@[H,H]); c3[l] = c2[l] @ Wa1[l]
// ---------------------------------------------------------------------------
__global__ __launch_bounds__(256) void w3_kernel(
    const float* __restrict__ W2, const float* __restrict__ c2,
    const float* __restrict__ Wa1,
    float* __restrict__ W3, float* __restrict__ c3)
{
    int idx = blockIdx.x * 256 + threadIdx.x;
    const int total = LL * (KK + 1) * HH;
    if (idx >= total) return;
    int h  = idx % HH;
    int kk = (idx / HH) % (KK + 1);
    int l  = idx / (HH * (KK + 1));
    const float* Wa = Wa1 + l * HH * HH;
    if (kk < KK) {
        const float* row = W2 + (l * KK + kk) * HH;
        float acc = 0.f;
        #pragma unroll 8
        for (int m = 0; m < HH; ++m) acc += row[m] * Wa[m * HH + h];
        W3[(l * KK + kk) * HH + h] = acc;
    } else {
        const float* row = c2 + l * HH;
        float acc = 0.f;
        #pragma unroll 8
        for (int m = 0; m < HH; ++m) acc += row[m] * Wa[m * HH + h];
        c3[l * HH + h] = acc;
    }
}

// ---------------------------------------------------------------------------
// chain_kernel: per-atom MLP chain, register-tiled.
// Block = 256 threads, AT=16 atoms. Thread: channel hh = tid&127,
// atom-half sh = tid>>7 (8 atoms). 8 accumulators/thread.
//   h = X@We + be
//   per l: t = silu(S@W3[l] + cnt*c3[l] + ba1[l]); h += t@Wa2[l] + ba2[l]
//   o = valid * (dot(silu(h@Wo1+bo1), Wo2) + bo2)
// ---------------------------------------------------------------------------
#define AT 16
#define ATP (AT + 4)   // padded row: 20 floats -> 16B-aligned float4 slots, 8-way banks

__global__ __launch_bounds__(256) void chain_kernel(
    const float* __restrict__ X, const int* __restrict__ batch,
    const float* __restrict__ We, const float* __restrict__ be,
    const float* __restrict__ ba1,
    const float* __restrict__ Wa2, const float* __restrict__ ba2,
    const float* __restrict__ Wo1, const float* __restrict__ bo1,
    const float* __restrict__ Wo2, const float* __restrict__ bo2,
    const float* __restrict__ S, const float* __restrict__ W3,
    const float* __restrict__ c3, const float* __restrict__ cnt,
    float* __restrict__ o_ws)
{
    __shared__ __align__(16) float sS[KK][ATP];
    __shared__ __align__(16) float tb[HH][ATP];
    __shared__ __align__(16) float sX[FF][ATP];
    __shared__ float pr[4][8];
    __shared__ float svalid[AT];

    const int tid = threadIdx.x;
    const int hh  = tid & 127;
    const int sh  = tid >> 7;            // atom half: atoms sh*8 .. sh*8+7
    const int a0  = blockIdx.x * AT;     // 96 % 16 == 0 -> whole block in one molecule
    const int b   = a0 / NN;
    const float cb = cnt[b];

    // ---- stage S^T, X^T, validity ----
    {
        int k = tid & 63, al = tid >> 6;
        #pragma unroll
        for (int r = 0; r < AT / 4; ++r)
            sS[k][al + r * 4] = S[(a0 + al + r * 4) * KK + k];
    }
    {
        int f = tid & 15, al = tid >> 4;  // 256 threads = 16*16 exactly
        sX[f][al] = X[(a0 + al) * FF + f];
    }
    if (tid < AT) svalid[tid] = (batch[a0 + tid] != -1) ? 1.f : 0.f;
    __syncthreads();

    // ---- embedding: h = X@We + be ----
    float h[8];
    {
        float acc[8] = {0, 0, 0, 0, 0, 0, 0, 0};
        const float* wp = We + hh;
        #pragma unroll
        for (int f = 0; f < FF; ++f) {
            float w = wp[f * HH];
            float4 u0 = *(const float4*)&sX[f][sh * 8];
            float4 u1 = *(const float4*)&sX[f][sh * 8 + 4];
            acc[0] += w * u0.x; acc[1] += w * u0.y; acc[2] += w * u0.z; acc[3] += w * u0.w;
            acc[4] += w * u1.x; acc[5] += w * u1.y; acc[6] += w * u1.z; acc[7] += w * u1.w;
        }
        float bee = be[hh];
        #pragma unroll
        for (int a = 0; a < 8; ++a) h[a] = acc[a] + bee;
    }

    // ---- layers ----
    for (int l = 0; l < LL; ++l) {
        float acc[8] = {0, 0, 0, 0, 0, 0, 0, 0};
        const float* wp = W3 + l * KK * HH + hh;
        #pragma unroll 8
        for (int k = 0; k < KK; ++k) {
            float w = wp[k * HH];
            float4 u0 = *(const float4*)&sS[k][sh * 8];
            float4 u1 = *(const float4*)&sS[k][sh * 8 + 4];
            acc[0] += w * u0.x; acc[1] += w * u0.y; acc[2] += w * u0.z; acc[3] += w * u0.w;
            acc[4] += w * u1.x; acc[5] += w * u1.y; acc[6] += w * u1.z; acc[7] += w * u1.w;
        }
        float bias = cb * c3[l * HH + hh] + ba1[l * HH + hh];

        __syncthreads();   // prev consumers of tb done
        {
            float4 t0, t1;
            float v;
            v = acc[0] + bias; t0.x = v / (1.f + __expf(-v));
            v = acc[1] + bias; t0.y = v / (1.f + __expf(-v));
            v = acc[2] + bias; t0.z = v / (1.f + __expf(-v));
            v = acc[3] + bias; t0.w = v / (1.f + __expf(-v));
            v = acc[4] + bias; t1.x = v / (1.f + __expf(-v));
            v = acc[5] + bias; t1.y = v / (1.f + __expf(-v));
            v = acc[6] + bias; t1.z = v / (1.f + __expf(-v));
            v = acc[7] + bias; t1.w = v / (1.f + __expf(-v));
            *(float4*)&tb[hh][sh * 8]     = t0;
            *(float4*)&tb[hh][sh * 8 + 4] = t1;
        }
        __syncthreads();

        float acc2[8] = {0, 0, 0, 0, 0, 0, 0, 0};
        const float* wq = Wa2 + l * HH * HH + hh;
        #pragma unroll 8
        for (int m = 0; m < HH; ++m) {
            float w = wq[m * HH];
            float4 u0 = *(const float4*)&tb[m][sh * 8];
            float4 u1 = *(const float4*)&tb[m][sh * 8 + 4];
            acc2[0] += w * u0.x; acc2[1] += w * u0.y; acc2[2] += w * u0.z; acc2[3] += w * u0.w;
            acc2[4] += w * u1.x; acc2[5] += w * u1.y; acc2[6] += w * u1.z; acc2[7] += w * u1.w;
        }
        float b2 = ba2[l * HH + hh];
        #pragma unroll
        for (int a = 0; a < 8; ++a) h[a] += acc2[a] + b2;
    }

    // ---- output head ----
    __syncthreads();
    *(float4*)&tb[hh][sh * 8]     = make_float4(h[0], h[1], h[2], h[3]);
    *(float4*)&tb[hh][sh * 8 + 4] = make_float4(h[4], h[5], h[6], h[7]);
    __syncthreads();

    float acc[8] = {0, 0, 0, 0, 0, 0, 0, 0};
    const float* wp = Wo1 + hh;
    #pragma unroll 8
    for (int m = 0; m < HH; ++m) {
        float w = wp[m * HH];
        float4 u0 = *(const float4*)&tb[m][sh * 8];
        float4 u1 = *(const float4*)&tb[m][sh * 8 + 4];
        acc[0] += w * u0.x; acc[1] += w * u0.y; acc[2] += w * u0.z; acc[3] += w * u0.w;
        acc[4] += w * u1.x; acc[5] += w * u1.y; acc[6] += w * u1.z; acc[7] += w * u1.w;
    }
    float bo = bo1[hh], wo2 = Wo2[hh];
    float contrib[8];
    #pragma unroll
    for (int a = 0; a < 8; ++a) {
        float v = acc[a] + bo;
        contrib[a] = (v / (1.f + __expf(-v))) * wo2;
    }
    // reduce over channels: each wave 64 lanes, then combine 2 waves per atom-half
    #pragma unroll
    for (int a = 0; a < 8; ++a) {
        float r = contrib[a];
        for (int off = 32; off > 0; off >>= 1) r += __shfl_down(r, off);
        contrib[a] = r;
    }
    if ((tid & 63) == 0) {
        int w = tid >> 6;
        #pragma unroll
        for (int a = 0; a < 8; ++a) pr[w][a] = contrib[a];
    }
    __syncthreads();
    if (tid < AT) {
        int shh = tid >> 3, ai = tid & 7;
        float o = pr[2 * shh][ai] + pr[2 * shh + 1][ai] + bo2[0];
        o_ws[a0 + tid] = svalid[tid] * o;
    }
}

// ---------------------------------------------------------------------------
// reduce_kernel: out[b] = sum_j o[b,j] / cnt[b]
// ---------------------------------------------------------------------------
__global__ __launch_bounds__(128) void reduce_kernel(
    const float* __restrict__ o_ws, const float* __restrict__ cnt,
    float* __restrict__ out)
{
    __shared__ float part[2];
    int b = blockIdx.x, t = threadIdx.x;
    float v = (t < NN) ? o_ws[b * NN + t] : 0.f;
    for (int off = 32; off > 0; off >>= 1) v += __shfl_down(v, off);
    if ((t & 63) == 0) part[t >> 6] = v;
    __syncthreads();
    if (t == 0) out[b] = (part[0] + part[1]) / cnt[b];
}

extern "C" void kernel_launch(void* const* d_in, const int* in_sizes, int n_in,
                              void* d_out, int out_size, void* d_ws, size_t ws_size,
                              hipStream_t stream) {
    const float* X     = (const float*)d_in[0];
    const float* R     = (const float*)d_in[1];
    const int*   batch = (const int*)  d_in[2];
    const float* We    = (const float*)d_in[3];
    const float* be    = (const float*)d_in[4];
    const float* Wrbf  = (const float*)d_in[5];
    const float* brbf  = (const float*)d_in[6];
    const float* Wpair = (const float*)d_in[7];
    const float* bpair = (const float*)d_in[8];
    const float* ba1   = (const float*)d_in[10];
    const float* Wa1   = (const float*)d_in[9];
    const float* Wa2   = (const float*)d_in[11];
    const float* ba2   = (const float*)d_in[12];
    const float* Wo1   = (const float*)d_in[13];
    const float* bo1   = (const float*)d_in[14];
    const float* Wo2   = (const float*)d_in[15];
    const float* bo2   = (const float*)d_in[16];

    float* w   = (float*)d_ws;
    float* S   = w;                        // B*N*K = 393216
    float* W2  = S  + BB * NN * KK;        // L*K*H = 24576
    float* c2  = W2 + LL * KK * HH;        // L*H   = 384
    float* W3  = c2 + LL * HH;             // L*K*H = 24576
    float* c3  = W3 + LL * KK * HH;        // L*H   = 384
    float* cnt = c3 + LL * HH;             // B     = 64
    float* ow  = cnt + BB;                 // B*N   = 6144
    float* out = (float*)d_out;

    hipLaunchKernelGGL(pre_kernel, dim3(W2_BLOCKS + CNT_BLOCKS + S_BLOCKS), dim3(256),
                       0, stream, Wrbf, brbf, Wpair, bpair, batch, R, W2, c2, cnt, S);
    hipLaunchKernelGGL(w3_kernel, dim3(W2_BLOCKS), dim3(256), 0, stream,
                       W2, c2, Wa1, W3, c3);
    hipLaunchKernelGGL(chain_kernel, dim3(BB * NN / AT), dim3(256), 0, stream,
                       X, batch, We, be, ba1, Wa2, ba2, Wo1, bo1, Wo2, bo2,
                       S, W3, c3, cnt, ow);
    hipLaunchKernelGGL(reduce_kernel, dim3(BB), dim3(128), 0, stream, ow, cnt, out);
}